// Round 3
// baseline (264.954 us; speedup 1.0000x reference)
//
#include <hip/hip_runtime.h>
#include <math.h>

#define NB 15

// acc layout in d_ws: [0..14]=counts, [15..29]=sum_u, [30..44]=sum_err  (45 floats)

__device__ __forceinline__ void row_stats(const float lv[10], int lab, int N_ok,
                                          int& bin, float& u, int& e10)
{
    float m = lv[0];
#pragma unroll
    for (int j = 1; j < 10; ++j) m = fmaxf(m, lv[j]);

    const float c = 1.44269504088896340736f;
    float mc = m * c;
    float Z = 0.0f, S = 0.0f;
#pragma unroll
    for (int j = 0; j < 10; ++j) {
        float e = exp2f(fmaf(lv[j], c, -mc));
        Z += e;
        S = fmaf(e, e, S);
    }
    float ratio = S * __builtin_amdgcn_rcpf(Z * Z);   // sum(p^2)
    u = -log2f(ratio + 1e-12f);

    bool valid = N_ok && (u >= 0.0f) && (u < 1.0f);
    bin = -1;
    if (valid) {
        bin = (int)(u * 15.0f);
        if (bin > 14) bin = 14;
    }
    if (!valid) u = 0.0f;

    // logit at label via cndmask chain (registers aren't indexable)
    float lvl = lv[0];
#pragma unroll
    for (int j = 1; j < 10; ++j) lvl = (lab == j) ? lv[j] : lvl;
    e10 = (lvl != m) ? 1 : 0;   // wrong iff label's logit isn't the max
}

__global__ __launch_bounds__(256, 4) void bin_kernel(
    const float* __restrict__ logits,
    const int* __restrict__ labels,
    float* __restrict__ acc,
    int N)
{
    __shared__ float s_acc[3 * NB];
    const int t = threadIdx.x;
    if (t < 3 * NB) s_acc[t] = 0.0f;

    // private accumulators: pk = count | (err_count<<16), su = sum of u
    int   pk[NB];
    float su[NB];
#pragma unroll
    for (int b = 0; b < NB; ++b) { pk[b] = 0; su[b] = 0.0f; }

    const float2* __restrict__ src2 = (const float2*)logits;
    const int stride = gridDim.x * 256;          // total threads
    int r = blockIdx.x * 256 + t;

    // main loop: two rows in flight per iteration for MLP
    for (; r + stride < N; r += 2 * stride) {
        const int r2i = r + stride;
        float a[10], b2[10];
        {
            const float2* p = src2 + (long long)r * 5;
#pragma unroll
            for (int j = 0; j < 5; ++j) { float2 w = p[j]; a[2*j] = w.x; a[2*j+1] = w.y; }
        }
        {
            const float2* p = src2 + (long long)r2i * 5;
#pragma unroll
            for (int j = 0; j < 5; ++j) { float2 w = p[j]; b2[2*j] = w.x; b2[2*j+1] = w.y; }
        }
        int labA = labels[r];
        int labB = labels[r2i];

        int binA, eA, binB, eB;
        float uA, uB;
        row_stats(a,  labA, 1, binA, uA, eA);
        row_stats(b2, labB, 1, binB, uB, eB);

        int incA = 1 + (eA << 16);
        int incB = 1 + (eB << 16);
#pragma unroll
        for (int b = 0; b < NB; ++b) {
            bool mA = (binA == b);
            bool mB = (binB == b);
            pk[b] += (mA ? incA : 0) + (mB ? incB : 0);
            su[b] += (mA ? uA : 0.0f) + (mB ? uB : 0.0f);
        }
    }
    // tail: at most one more row per thread
    if (r < N) {
        float a[10];
        const float2* p = src2 + (long long)r * 5;
#pragma unroll
        for (int j = 0; j < 5; ++j) { float2 w = p[j]; a[2*j] = w.x; a[2*j+1] = w.y; }
        int lab = labels[r];
        int bin, e10; float u;
        row_stats(a, lab, 1, bin, u, e10);
        int inc = 1 + (e10 << 16);
#pragma unroll
        for (int b = 0; b < NB; ++b) {
            bool mt = (bin == b);
            pk[b] += mt ? inc : 0;
            su[b] += mt ? u : 0.0f;
        }
    }

    // once-per-block reduction: wave butterfly -> shared atomics -> global atomics
    const int lane = t & 63;
#pragma unroll
    for (int b = 0; b < NB; ++b) {
        int   p = pk[b];
        float s = su[b];
#pragma unroll
        for (int off = 1; off < 64; off <<= 1) {
            p += __shfl_xor(p, off, 64);
            s += __shfl_xor(s, off, 64);
        }
        if (lane == 0) {
            atomicAdd(&s_acc[b],          (float)(p & 0xFFFF));
            atomicAdd(&s_acc[NB + b],     s);
            atomicAdd(&s_acc[2 * NB + b], (float)(p >> 16));
        }
    }
    __syncthreads();
    if (t < 3 * NB) {
        float v = s_acc[t];
        if (v != 0.0f) atomicAdd(&acc[t], v);
    }
}

__global__ void finalize_kernel(const float* __restrict__ acc,
                                float* __restrict__ out, float n)
{
    int b = threadIdx.x;
    float gap = 0.0f;
    if (b < NB) {
        float cnt = acc[b];
        if (cnt > 0.0f) {
            float u_b   = acc[NB + b] / cnt;
            float err_b = acc[2 * NB + b] / cnt;
            float inner = 2.0f * exp2f(-u_b) - 1.0f;
            if (inner < 0.0f) inner = 0.0f;
            float r_ref = 0.5f * (1.0f - sqrtf(inner));
            gap = fabsf(err_b - r_ref) * (cnt / n);
        }
    }
#pragma unroll
    for (int off = 32; off >= 1; off >>= 1)
        gap += __shfl_xor(gap, off, 64);
    if (b == 0) out[0] = gap;
}

extern "C" void kernel_launch(void* const* d_in, const int* in_sizes, int n_in,
                              void* d_out, int out_size, void* d_ws, size_t ws_size,
                              hipStream_t stream)
{
    const float* logits = (const float*)d_in[0];
    const int*   labels = (const int*)d_in[1];
    const int N = in_sizes[1];              // labels count = number of rows

    float* acc = (float*)d_ws;              // 45 floats
    hipMemsetAsync(acc, 0, 3 * NB * sizeof(float), stream);

    int blocks = 2048;
    int maxBlocks = (N + 255) / 256;
    if (blocks > maxBlocks) blocks = maxBlocks;
    bin_kernel<<<blocks, 256, 0, stream>>>(logits, labels, acc, N);
    finalize_kernel<<<1, 64, 0, stream>>>(acc, (float*)d_out, (float)N);
}

// Round 4
// 251.016 us; speedup vs baseline: 1.0555x; 1.0555x over previous
//
#include <hip/hip_runtime.h>
#include <math.h>

#define NB 15
#define TROWS 256            // rows per tile
#define TF4   640            // float4 per tile = 256*10/4
#define LSTRIDE 11           // padded floats per LDS row (odd -> conflict-free reads)

// acc layout in d_ws: [0..14]=counts, [15..29]=sum_u, [30..44]=sum_err  (45 floats)

__device__ __forceinline__ void scatter4(float* lds, int li, float4 v)
{
    // float4 #li covers global floats f..f+3 of this tile; place into padded rows.
    unsigned f   = (unsigned)li * 4u;
    unsigned row = f / 10u;                  // compiler emits magic-mul
    unsigned off = f - row * 10u;            // always even: {0,2,4,6,8}
    unsigned a0  = row * LSTRIDE + off;
    lds[a0]     = v.x;
    lds[a0 + 1] = v.y;
    // floats f+2,f+3: wrap to next row's offset 0 when off==8 (a0+3 == (row+1)*11)
    unsigned a1 = (off == 8u) ? (a0 + 3u) : (a0 + 2u);
    lds[a1]     = v.z;
    lds[a1 + 1] = v.w;
}

__global__ __launch_bounds__(256) void bin_kernel(
    const float* __restrict__ logits,
    const int* __restrict__ labels,
    float* __restrict__ acc,
    int N, int numTiles)
{
    __shared__ float lds[TROWS * LSTRIDE];   // 11,264 B
    __shared__ float s_acc[3 * NB];

    const int t = threadIdx.x;
    if (t < 3 * NB) s_acc[t] = 0.0f;

    // private accumulators: pk = count | (err_count<<16), su = sum of u
    int   pk[NB];
    float su[NB];
#pragma unroll
    for (int b = 0; b < NB; ++b) { pk[b] = 0; su[b] = 0.0f; }

    const float4* __restrict__ src4 = (const float4*)logits;
    const long long totF4 = ((long long)N * 10) >> 2;
    const float4 zero4 = make_float4(0.f, 0.f, 0.f, 0.f);

    for (int tile = blockIdx.x; tile < numTiles; tile += gridDim.x) {
        // ---- issue coalesced staging loads BEFORE the barrier (latency absorbed by wait)
        const long long base = (long long)tile * TF4;
        long long g0 = base + t;
        long long g1 = base + t + 256;
        long long g2 = base + t + 512;
        float4 v0 = (g0 < totF4) ? src4[g0] : zero4;
        float4 v1 = (g1 < totF4) ? src4[g1] : zero4;
        float4 v2 = zero4;
        const bool has2 = (t < TF4 - 512);   // t < 128
        if (has2 && g2 < totF4) v2 = src4[g2];

        const int gr  = tile * TROWS + t;
        const int lab = (gr < N) ? labels[gr] : 0;

        __syncthreads();                     // previous tile fully consumed
        scatter4(lds, t,       v0);
        scatter4(lds, t + 256, v1);
        if (has2) scatter4(lds, t + 512, v2);
        __syncthreads();                     // tile staged

        // ---- compute own row from LDS (stride-11: conflict-free)
        const float* r = lds + t * LSTRIDE;
        float lv[10];
#pragma unroll
        for (int j = 0; j < 10; ++j) lv[j] = r[j];

        float m = lv[0];
#pragma unroll
        for (int j = 1; j < 10; ++j) m = fmaxf(m, lv[j]);

        const float c = 1.44269504088896340736f;
        float mc = m * c;
        float Z = 0.0f, S = 0.0f;
#pragma unroll
        for (int j = 0; j < 10; ++j) {
            float e = exp2f(fmaf(lv[j], c, -mc));
            Z += e;
            S = fmaf(e, e, S);
        }
        float ratio = S * __builtin_amdgcn_rcpf(Z * Z);   // sum(p^2)
        float u = -log2f(ratio + 1e-12f);

        // zero-filled (OOB) rows give u = log2(10) > 1 -> invalid -> excluded
        bool valid = (u >= 0.0f) && (u < 1.0f);
        int bin = -1;
        if (valid) {
            bin = (int)(u * 15.0f);
            if (bin > 14) bin = 14;
        }
        float uu = valid ? u : 0.0f;

        float lvl = r[lab];                  // label's logit via dynamic LDS read
        int e10 = (lvl != m) ? 1 : 0;        // wrong iff label's logit isn't the max
        int inc = 1 + (e10 << 16);

#pragma unroll
        for (int b = 0; b < NB; ++b) {
            bool mt = (bin == b);
            pk[b] += mt ? inc : 0;
            su[b] += mt ? uu : 0.0f;
        }
    }

    // ---- once-per-block reduction: wave butterfly -> shared atomics -> global atomics
    const int lane = t & 63;
#pragma unroll
    for (int b = 0; b < NB; ++b) {
        int   p = pk[b];
        float s = su[b];
#pragma unroll
        for (int off = 1; off < 64; off <<= 1) {
            p += __shfl_xor(p, off, 64);
            s += __shfl_xor(s, off, 64);
        }
        if (lane == 0) {
            atomicAdd(&s_acc[b],          (float)(p & 0xFFFF));
            atomicAdd(&s_acc[NB + b],     s);
            atomicAdd(&s_acc[2 * NB + b], (float)(p >> 16));
        }
    }
    __syncthreads();
    if (t < 3 * NB) {
        float v = s_acc[t];
        if (v != 0.0f) atomicAdd(&acc[t], v);
    }
}

__global__ void finalize_kernel(const float* __restrict__ acc,
                                float* __restrict__ out, float n)
{
    int b = threadIdx.x;
    float gap = 0.0f;
    if (b < NB) {
        float cnt = acc[b];
        if (cnt > 0.0f) {
            float u_b   = acc[NB + b] / cnt;
            float err_b = acc[2 * NB + b] / cnt;
            float inner = 2.0f * exp2f(-u_b) - 1.0f;
            if (inner < 0.0f) inner = 0.0f;
            float r_ref = 0.5f * (1.0f - sqrtf(inner));
            gap = fabsf(err_b - r_ref) * (cnt / n);
        }
    }
#pragma unroll
    for (int off = 32; off >= 1; off >>= 1)
        gap += __shfl_xor(gap, off, 64);
    if (b == 0) out[0] = gap;
}

extern "C" void kernel_launch(void* const* d_in, const int* in_sizes, int n_in,
                              void* d_out, int out_size, void* d_ws, size_t ws_size,
                              hipStream_t stream)
{
    const float* logits = (const float*)d_in[0];
    const int*   labels = (const int*)d_in[1];
    const int N = in_sizes[1];               // labels count = number of rows

    float* acc = (float*)d_ws;               // 45 floats
    hipMemsetAsync(acc, 0, 3 * NB * sizeof(float), stream);

    const int numTiles = (N + TROWS - 1) / TROWS;
    int blocks = numTiles < 2048 ? numTiles : 2048;
    bin_kernel<<<blocks, 256, 0, stream>>>(logits, labels, acc, N, numTiles);
    finalize_kernel<<<1, 64, 0, stream>>>(acc, (float*)d_out, (float)N);
}

// Round 5
// 245.886 us; speedup vs baseline: 1.0776x; 1.0209x over previous
//
#include <hip/hip_runtime.h>
#include <math.h>
#include <stdint.h>

#define NB 15
#define TROWS 512                 // rows per tile (2 per thread)
#define TBYTES (TROWS * 40)       // 20480 B per tile
#define NCOPY 8                   // spread accumulator copies (contention /8)
#define ACCSTRIDE 64              // floats per copy (line-separated)

// d_ws: NCOPY copies of [0..14]=counts, [15..29]=sum_u, [30..44]=sum_err

__device__ __forceinline__ void gload_lds16(const void* g, float* ldsBase, uint32_t ldsByteOff)
{
    // async global->LDS, 16 B/lane; LDS dest = wave-uniform base + lane*16 (HW)
    __builtin_amdgcn_global_load_lds(
        (const __attribute__((address_space(1))) uint32_t*)g,
        (__attribute__((address_space(3))) uint32_t*)((char*)ldsBase + ldsByteOff),
        16, 0, 0);
}

__device__ __forceinline__ void row_stats(const float lv[10], float lvl_lab, bool rowOK,
                                          int& bin, float& u, int& e10)
{
    float m = lv[0];
#pragma unroll
    for (int j = 1; j < 10; ++j) m = fmaxf(m, lv[j]);

    const float c = 1.44269504088896340736f;
    float mc = m * c;
    float Z = 0.0f, S = 0.0f;
#pragma unroll
    for (int j = 0; j < 10; ++j) {
        float e = exp2f(fmaf(lv[j], c, -mc));
        Z += e;
        S = fmaf(e, e, S);
    }
    float ratio = S * __builtin_amdgcn_rcpf(Z * Z);   // sum(p^2)
    u = -log2f(ratio + 1e-12f);

    bool valid = rowOK && (u >= 0.0f) && (u < 1.0f);  // LDS garbage rows gated by rowOK
    bin = -1;
    if (valid) {
        bin = (int)(u * 15.0f);
        if (bin > 14) bin = 14;
    }
    if (!valid) u = 0.0f;
    e10 = (lvl_lab != m) ? 1 : 0;     // wrong iff label's logit isn't the max
}

__global__ __launch_bounds__(256) void bin_kernel(
    const float* __restrict__ logits,
    const int* __restrict__ labels,
    float* __restrict__ acc,
    int N, int numTiles)
{
    __shared__ float lds[TROWS * 10];     // 20480 B, unpadded (global_load_lds layout)
    __shared__ float s_acc[3 * NB];

    const int t = threadIdx.x;
    if (t < 3 * NB) s_acc[t] = 0.0f;
    const int wid  = t >> 6;
    const int lane = t & 63;

    int   pk[NB];                          // count | (err<<16)
    float su[NB];
#pragma unroll
    for (int b = 0; b < NB; ++b) { pk[b] = 0; su[b] = 0.0f; }

    const char* srcB = (const char*)logits;
    const long long totB = (long long)N * 40;   // N*40 assumed 16B-divisible (N=4M)

    for (int tile = blockIdx.x; tile < numTiles; tile += gridDim.x) {
        const long long tb = (long long)tile * TBYTES;

        const int r0 = tile * TROWS + t;
        const int r1 = r0 + 256;
        const int lab0 = (r0 < N) ? labels[r0] : 0;
        const int lab1 = (r1 < N) ? labels[r1] : 0;

        __syncthreads();                   // previous tile fully consumed
        // 20 chunks of 1024 B; 5 per wave, async DMA straight into LDS
#pragma unroll
        for (int k = 0; k < 5; ++k) {
            uint32_t loff = (uint32_t)(wid * 5 + k) << 10;     // wave-uniform
            long long gb = tb + loff + lane * 16;
            if (gb < totB)
                gload_lds16(srcB + gb, lds, __builtin_amdgcn_readfirstlane(loff));
        }
        __syncthreads();                   // vmcnt(0) drain + barrier -> LDS ready

        // ---- two rows per thread ----
        float a[10], b2[10];
        {
            const float2* p = (const float2*)(lds + t * 10);
#pragma unroll
            for (int j = 0; j < 5; ++j) { float2 w = p[j]; a[2*j] = w.x; a[2*j+1] = w.y; }
        }
        {
            const float2* p = (const float2*)(lds + (t + 256) * 10);
#pragma unroll
            for (int j = 0; j < 5; ++j) { float2 w = p[j]; b2[2*j] = w.x; b2[2*j+1] = w.y; }
        }
        float lvl0 = lds[t * 10 + lab0];           // label logit, dynamic LDS read
        float lvl1 = lds[(t + 256) * 10 + lab1];

        int binA, eA, binB, eB;
        float uA, uB;
        row_stats(a,  lvl0, r0 < N, binA, uA, eA);
        row_stats(b2, lvl1, r1 < N, binB, uB, eB);

        int incA = 1 + (eA << 16);
        int incB = 1 + (eB << 16);
#pragma unroll
        for (int b = 0; b < NB; ++b) {
            bool mA = (binA == b);
            bool mB = (binB == b);
            pk[b] += (mA ? incA : 0) + (mB ? incB : 0);
            su[b] += (mA ? uA : 0.0f) + (mB ? uB : 0.0f);
        }
    }

    // ---- once-per-block: wave butterfly -> shared atomics -> spread global atomics
#pragma unroll
    for (int b = 0; b < NB; ++b) {
        int   p = pk[b];
        float s = su[b];
#pragma unroll
        for (int off = 1; off < 64; off <<= 1) {
            p += __shfl_xor(p, off, 64);
            s += __shfl_xor(s, off, 64);
        }
        if (lane == 0) {
            atomicAdd(&s_acc[b],          (float)(p & 0xFFFF));
            atomicAdd(&s_acc[NB + b],     s);
            atomicAdd(&s_acc[2 * NB + b], (float)(p >> 16));
        }
    }
    __syncthreads();
    if (t < 3 * NB) {
        float v = s_acc[t];
        if (v != 0.0f)
            atomicAdd(&acc[(blockIdx.x & (NCOPY - 1)) * ACCSTRIDE + t], v);
    }
}

__global__ void finalize_kernel(const float* __restrict__ acc,
                                float* __restrict__ out, float n)
{
    int b = threadIdx.x;
    float gap = 0.0f;
    if (b < NB) {
        float cnt = 0.0f, sumu = 0.0f, serr = 0.0f;
#pragma unroll
        for (int c = 0; c < NCOPY; ++c) {
            cnt  += acc[c * ACCSTRIDE + b];
            sumu += acc[c * ACCSTRIDE + NB + b];
            serr += acc[c * ACCSTRIDE + 2 * NB + b];
        }
        if (cnt > 0.0f) {
            float u_b   = sumu / cnt;
            float err_b = serr / cnt;
            float inner = 2.0f * exp2f(-u_b) - 1.0f;
            if (inner < 0.0f) inner = 0.0f;
            float r_ref = 0.5f * (1.0f - sqrtf(inner));
            gap = fabsf(err_b - r_ref) * (cnt / n);
        }
    }
#pragma unroll
    for (int off = 32; off >= 1; off >>= 1)
        gap += __shfl_xor(gap, off, 64);
    if (b == 0) out[0] = gap;
}

extern "C" void kernel_launch(void* const* d_in, const int* in_sizes, int n_in,
                              void* d_out, int out_size, void* d_ws, size_t ws_size,
                              hipStream_t stream)
{
    const float* logits = (const float*)d_in[0];
    const int*   labels = (const int*)d_in[1];
    const int N = in_sizes[1];                  // labels count = number of rows

    float* acc = (float*)d_ws;                  // NCOPY * ACCSTRIDE floats
    hipMemsetAsync(acc, 0, NCOPY * ACCSTRIDE * sizeof(float), stream);

    const int numTiles = (N + TROWS - 1) / TROWS;
    int blocks = numTiles < 1792 ? numTiles : 1792;   // 7 blocks/CU (LDS-limited)
    bin_kernel<<<blocks, 256, 0, stream>>>(logits, labels, acc, N, numTiles);
    finalize_kernel<<<1, 64, 0, stream>>>(acc, (float*)d_out, (float)N);
}